// Round 1
// baseline (85.727 us; speedup 1.0000x reference)
//
#include <hip/hip_runtime.h>
#include <math.h>

// LongRangeProj forward, MI355X.
// Shapes: B=2, C=64, NH=NW=8, H=W=64, STRIDE=8.
// out[b,c,h,w] = max_{i,j} x[b,c,i,j] * exp(-(fn-|rm|)^2 * inv2rs) * exp(-acos(cc)^2 * inv2as)
// Computed in log-space: exp( max_{i,j} [ ln x + -(fn-rm)^2*inv2rs - ang^2*inv2as ] ).

#define PI_F 3.14159265358979323846f

__device__ __forceinline__ float acos_as(float u) {
    // Abramowitz & Stegun 4.4.45: acos(u) = sqrt(1-u)*poly(u) for u in [0,1],
    // |err| <= ~2e-8. Caller folds sign: acos(-u) = pi - acos(u).
    float p = -0.0012624911f;
    p = fmaf(p, u,  0.0066700901f);
    p = fmaf(p, u, -0.0170881256f);
    p = fmaf(p, u,  0.0308918810f);
    p = fmaf(p, u, -0.0501743046f);
    p = fmaf(p, u,  0.0889789874f);
    p = fmaf(p, u, -0.2145988016f);
    p = fmaf(p, u,  1.5707963050f);
    return __builtin_amdgcn_sqrtf(1.0f - u) * p;
}

__device__ __forceinline__ float term_arg(float dx2, float dy2, float dy,
                                          float cadx, float sa,
                                          float rm, float lx,
                                          float inv2rs, float inv2as) {
    const float r2  = dx2 + dy2;
    const float rfn = __builtin_amdgcn_rsqf(r2);   // v_rsq_f32; inf at r2==0
    float fn  = r2 * rfn;                          // NaN at r2==0 (fixed below)
    const float num = fmaf(sa, dy, cadx);
    float cr  = num * rfn;
    cr = fminf(fmaxf(cr, -1.0f), 1.0f);
    const bool z = (r2 == 0.0f);                   // the mask point (h==8i, w==8j)
    const float cc = z ? 1.0f : cr;
    fn = z ? 0.0f : fn;
    const float u  = fabsf(cc);
    const float a  = acos_as(u);
    const float ang = (cc >= 0.0f) ? a : (PI_F - a);
    const float t  = fn - rm;
    // arg = lx - t^2*inv2rs - ang^2*inv2as
    return fmaf(-(t * t), inv2rs, fmaf(-(ang * ang), inv2as, lx));
}

__global__ __launch_bounds__(256) void lrp_fwd(
    const float* __restrict__ x,
    const float* __restrict__ rmean,
    const float* __restrict__ amean,
    const float* __restrict__ rstd,
    const float* __restrict__ astd,
    float* __restrict__ out)
{
    __shared__ float4 prm[64];   // {ln x, |rm|, cos, sin} per node (i,j)

    const int tid  = threadIdx.x;
    const int bc   = blockIdx.x >> 3;   // (b*64 + c), 8 blocks per plane
    const int tile = blockIdx.x & 7;    // 512 pixels per block

    if (tid < 64) {
        const int idx = bc * 64 + tid;
        const float lx = logf(x[idx]);          // accurate; x==0 -> -inf is fine
        const float rm = fabsf(rmean[idx]);
        float sa, ca;
        sincosf(amean[idx], &sa, &ca);          // accurate libm; setup only
        prm[tid] = make_float4(lx, rm, ca, sa);
    }

    const int c = bc & 63;
    const float rs = rstd[c];
    const float as = astd[c];
    const float inv2rs = 1.0f / (2.0f * fmaf(rs, rs, 0.01f));
    const float inv2as = 1.0f / (2.0f * fmaf(as, as, 1e-4f));

    __syncthreads();

    // Two pixels per thread: rows h and h+4, same column.
    const int   pp0 = tile * 512 + tid;
    const float wf  = (float)(pp0 & 63);
    const float h0f = (float)(pp0 >> 6);

    float acc0 = -INFINITY, acc1 = -INFINITY;

    for (int i = 0; i < 8; ++i) {
        const float dy0 = h0f - 8.0f * (float)i;
        const float dy1 = dy0 + 4.0f;
        const float dy0sq = dy0 * dy0;
        const float dy1sq = dy1 * dy1;
        #pragma unroll
        for (int j = 0; j < 8; ++j) {
            const float4 q   = prm[i * 8 + j];  // wave-uniform -> LDS broadcast
            const float dx   = wf - 8.0f * (float)j;
            const float dx2  = dx * dx;
            const float cadx = q.z * dx;
            acc0 = fmaxf(acc0, term_arg(dx2, dy0sq, dy0, cadx, q.w, q.y, q.x, inv2rs, inv2as));
            acc1 = fmaxf(acc1, term_arg(dx2, dy1sq, dy1, cadx, q.w, q.y, q.x, inv2rs, inv2as));
        }
    }

    out[bc * 4096 + pp0]       = expf(acc0);
    out[bc * 4096 + pp0 + 256] = expf(acc1);
}

extern "C" void kernel_launch(void* const* d_in, const int* in_sizes, int n_in,
                              void* d_out, int out_size, void* d_ws, size_t ws_size,
                              hipStream_t stream) {
    const float* x     = (const float*)d_in[0];
    const float* rmean = (const float*)d_in[1];
    const float* amean = (const float*)d_in[2];
    const float* rstd  = (const float*)d_in[3];
    const float* astd  = (const float*)d_in[4];
    float* out = (float*)d_out;

    // B*C = 128 planes, 8 blocks (of 512 px) per plane -> 1024 blocks.
    lrp_fwd<<<1024, 256, 0, stream>>>(x, rmean, amean, rstd, astd, out);
}

// Round 6
// 81.917 us; speedup vs baseline: 1.0465x; 1.0465x over previous
//
#include <hip/hip_runtime.h>
#include <math.h>

// LongRangeProj forward, MI355X. B=2,C=64,NH=NW=8,H=W=64,STRIDE=8.
// Log-space: out = exp( max_{i,j} [ ln x - (fn-rm)^2*inv2rs - acos(cc)^2*inv2as ] )
// Mask point (r2==0) falls out naturally: cr=NaN -> u=1 -> a=0, (NaN<0)=false -> ang=0,
// fn=sqrt(0)=0 -> arg = lx - rm^2*inv2rs == reference's masked value.

#define PI_F 3.14159265358979323846f

__global__ __launch_bounds__(256, 8) void lrp_fwd(
    const float* __restrict__ x,
    const float* __restrict__ rmean,
    const float* __restrict__ amean,
    const float* __restrict__ rstd,
    const float* __restrict__ astd,
    float* __restrict__ out)
{
    __shared__ float4 prm[64];   // {ln x, |rm|, cos, sin} per node (i,j)

    const int tid  = threadIdx.x;
    const int bc   = blockIdx.x >> 4;   // plane (b*64+c); 16 blocks per plane
    const int tile = blockIdx.x & 15;   // 256 pixels per block

    if (tid < 64) {
        const int idx = bc * 64 + tid;
        const float lx = logf(x[idx]);          // accurate; setup only
        const float rm = fabsf(rmean[idx]);
        float sa, ca;
        sincosf(amean[idx], &sa, &ca);          // accurate; setup only
        prm[tid] = make_float4(lx, rm, ca, sa);
    }

    const int c = bc & 63;
    const float rs = rstd[c];
    const float as = astd[c];
    const float inv2rs = 1.0f / (2.0f * fmaf(rs, rs, 0.01f));
    const float inv2as = 1.0f / (2.0f * fmaf(as, as, 1e-4f));

    __syncthreads();

    const int   pp = tile * 256 + tid;      // pixel in plane, 0..4095
    const float wf = (float)(pp & 63);
    const float hf = (float)(pp >> 6);

    // Per-column dx, hoisted. (dx^2 folds into the r2 FMA — no table needed,
    // keeps live VGPRs under the 64-reg cap imposed by launch_bounds(256,8).)
    float dxs[8];
    #pragma unroll
    for (int j = 0; j < 8; ++j) dxs[j] = wf - 8.0f * (float)j;

    float acc = -INFINITY;

    #pragma unroll 2
    for (int i = 0; i < 8; ++i) {
        const float dy  = hf - 8.0f * (float)i;
        const float dy2 = dy * dy;
        #pragma unroll
        for (int j = 0; j < 8; ++j) {
            const float4 q  = prm[i * 8 + j];     // wave-uniform -> LDS broadcast
            const float dx  = dxs[j];
            const float r2  = fmaf(dx, dx, dy2);
            const float rfn = __builtin_amdgcn_rsqf(r2);   // trans pipe
            const float fn  = __builtin_amdgcn_sqrtf(r2);  // trans pipe; 0 at r2==0
            const float num = fmaf(q.w, dy, q.z * dx);
            const float cr  = num * rfn;                   // NaN only at r2==0
            const float u   = fminf(fabsf(cr), 1.0f);      // minnum: NaN -> 1
            // acos(u) = sqrt(1-u)*p(u), A&S 4.4.45 4-term, |err|<=6.7e-5 rad
            float p = fmaf(-0.0187293f, u, 0.0742610f);
            p = fmaf(p, u, -0.2121144f);
            p = fmaf(p, u, 1.5707963f);
            const float a   = __builtin_amdgcn_sqrtf(1.0f - u) * p;
            const float ang = (cr < 0.0f) ? (PI_F - a) : a;   // NaN -> a = 0
            const float t   = fn - q.y;
            const float arg = fmaf(-(t * t), inv2rs,
                              fmaf(-(ang * ang), inv2as, q.x));
            acc = fmaxf(acc, arg);
        }
    }

    out[bc * 4096 + pp] = __expf(acc);
}

extern "C" void kernel_launch(void* const* d_in, const int* in_sizes, int n_in,
                              void* d_out, int out_size, void* d_ws, size_t ws_size,
                              hipStream_t stream) {
    const float* x     = (const float*)d_in[0];
    const float* rmean = (const float*)d_in[1];
    const float* amean = (const float*)d_in[2];
    const float* rstd  = (const float*)d_in[3];
    const float* astd  = (const float*)d_in[4];
    float* out = (float*)d_out;

    // 128 planes x 16 blocks (256 px each) = 2048 blocks -> 8192 waves = 8/SIMD.
    lrp_fwd<<<2048, 256, 0, stream>>>(x, rmean, amean, rstd, astd, out);
}

// Round 7
// 79.408 us; speedup vs baseline: 1.0796x; 1.0316x over previous
//
#include <hip/hip_runtime.h>
#include <math.h>

// LongRangeProj forward, MI355X. B=2,C=64,NH=NW=8,H=W=64,STRIDE=8.
// Log-space: out = exp( max_n [ ln x_n - (fn-rm_n)^2*inv2rs - ang_n^2*inv2as ] )
// with ang = acos(clip(cosang)) == |wrap(phi - theta)|, phi = atan2(dy,dx).
// Geometry (fn, phi) depends only on (node, pixel): 64*4096 float2 = 2 MB,
// precomputed into d_ws by lrp_geom, L2-resident, shared by all 128 planes.
// Mask point (dx=dy=0): reference forces ang=0; handled by fn==0 -> aa=0.
// Radius term at mask uses fn=0 (unmasked) -> arg = lx - rm^2*inv2rs. Matches.

#define TWO_PI_F   6.28318530717958647692f
#define INV_2PI_F  0.15915494309189533577f

__global__ __launch_bounds__(256) void lrp_geom(float2* __restrict__ tab)
{
    const int idx = blockIdx.x * 256 + threadIdx.x;   // 0..262143
    const int n   = idx >> 12;                        // node i*8+j
    const int pp  = idx & 4095;                       // pixel h*64+w
    const float dx = (float)(pp & 63) - 8.0f * (float)(n & 7);
    const float dy = (float)(pp >> 6) - 8.0f * (float)(n >> 3);
    const float fn = sqrtf(fmaf(dx, dx, dy * dy));    // exact 0 at node center
    const float ph = atan2f(dy, dx);                  // setup only; libm ok
    tab[idx] = make_float2(fn, ph);
}

__global__ __launch_bounds__(256, 8) void lrp_fwd(
    const float* __restrict__ x,
    const float* __restrict__ rmean,
    const float* __restrict__ amean,
    const float* __restrict__ rstd,
    const float* __restrict__ astd,
    const float2* __restrict__ tab,
    float* __restrict__ out)
{
    __shared__ float4 prm[64];   // {ln x, |rm|, theta, 0} per node

    const int tid  = threadIdx.x;
    const int bc   = blockIdx.x >> 4;   // plane (b*64+c); 16 blocks per plane
    const int tile = blockIdx.x & 15;   // 256 pixels per block

    if (tid < 64) {
        const int idx = bc * 64 + tid;
        prm[tid] = make_float4(logf(x[idx]), fabsf(rmean[idx]),
                               amean[idx], 0.0f);     // no trig needed now
    }

    const int c = bc & 63;
    const float rs = rstd[c];
    const float as = astd[c];
    const float inv2rs = 1.0f / (2.0f * fmaf(rs, rs, 0.01f));
    const float inv2as = 1.0f / (2.0f * fmaf(as, as, 1e-4f));

    __syncthreads();

    const int pp = tile * 256 + tid;    // pixel in plane, 0..4095

    float acc = -INFINITY;

    #pragma unroll 2
    for (int i = 0; i < 8; ++i) {
        #pragma unroll
        for (int j = 0; j < 8; ++j) {
            const int n = i * 8 + j;
            const float4 q = prm[n];            // wave-uniform LDS broadcast
            const float2 g = tab[n * 4096 + pp];// coalesced dwordx2, L2-hit
            // ang = |wrap(phi - theta)| in [0,pi]; sign dropped by squaring
            const float d   = g.y - q.z;
            const float k   = __builtin_rintf(d * INV_2PI_F);  // v_rndne
            const float ang = fmaf(k, -TWO_PI_F, d);
            const float aa  = (g.x == 0.0f) ? 0.0f : ang * ang; // mask point
            const float t   = g.x - q.y;
            const float arg = fmaf(-(t * t), inv2rs,
                              fmaf(-aa, inv2as, q.x));
            acc = fmaxf(acc, arg);
        }
    }

    out[bc * 4096 + pp] = __expf(acc);
}

extern "C" void kernel_launch(void* const* d_in, const int* in_sizes, int n_in,
                              void* d_out, int out_size, void* d_ws, size_t ws_size,
                              hipStream_t stream) {
    const float* x     = (const float*)d_in[0];
    const float* rmean = (const float*)d_in[1];
    const float* amean = (const float*)d_in[2];
    const float* rstd  = (const float*)d_in[3];
    const float* astd  = (const float*)d_in[4];
    float* out = (float*)d_out;
    float2* tab = (float2*)d_ws;        // 2 MB of scratch; rebuilt every call

    lrp_geom<<<1024, 256, 0, stream>>>(tab);
    // 128 planes x 16 blocks (256 px each) = 2048 blocks -> 8192 waves.
    lrp_fwd<<<2048, 256, 0, stream>>>(x, rmean, amean, rstd, astd, tab, out);
}

// Round 8
// 79.017 us; speedup vs baseline: 1.0849x; 1.0049x over previous
//
#include <hip/hip_runtime.h>
#include <math.h>

// LongRangeProj forward, MI355X. B=2,C=64,NH=NW=8,H=W=64,STRIDE=8.
// out = exp( max_n [ ln x_n - (fn-rm_n)^2*inv2rs - ang_n^2*inv2as ] ),
// ang = acos(clip(cos(phi-theta))) == min(|d|, 2pi-|d|), d = phi - theta_wrapped.
// Geometry depends only on (dx,dy), dx,dy in [-56,63]: 120x120 float2 strip
// table (115 KB) in d_ws — L1/L2-resident, shared by all planes and nodes.
// Mask point (dx=dy=0): the in-loop term is dominated by lx - rm^2*inv2rs
// (since aa>=0), so a center-pixel epilogue fmax reproduces the reference
// exactly; no per-term cndmask needed.

#define TWO_PI_F   6.28318530717958647692f
#define INV_2PI_F  0.15915494309189533577f

__global__ __launch_bounds__(256) void lrp_geom(float2* __restrict__ tab2)
{
    const int idx = blockIdx.x * 256 + threadIdx.x;   // 0..14399
    if (idx >= 14400) return;
    const float dy = (float)(idx / 120 - 56);
    const float dx = (float)(idx % 120 - 56);
    const float fn = sqrtf(fmaf(dx, dx, dy * dy));    // exact 0 at (0,0)
    const float ph = atan2f(dy, dx);                  // atan2(0,0)=0; setup only
    tab2[idx] = make_float2(fn, ph);
}

__global__ __launch_bounds__(256, 8) void lrp_fwd(
    const float* __restrict__ x,
    const float* __restrict__ rmean,
    const float* __restrict__ amean,
    const float* __restrict__ rstd,
    const float* __restrict__ astd,
    const float2* __restrict__ tab2,
    float* __restrict__ out)
{
    __shared__ float4 prm[64];   // {ln x, |rm|, theta_wrapped, 0} per node

    const int tid  = threadIdx.x;
    const int bc   = blockIdx.x >> 4;   // plane (b*64+c); 16 blocks per plane
    const int tile = blockIdx.x & 15;   // 256 pixels per block

    if (tid < 64) {
        const int idx = bc * 64 + tid;
        float th = amean[idx];
        th = fmaf(__builtin_rintf(th * INV_2PI_F), -TWO_PI_F, th); // -> [-pi,pi]
        prm[tid] = make_float4(logf(x[idx]), fabsf(rmean[idx]), th, 0.0f);
    }

    const int c = bc & 63;
    const float rs = rstd[c];
    const float as = astd[c];
    const float inv2rs = 1.0f / (2.0f * fmaf(rs, rs, 0.01f));
    const float inv2as = 1.0f / (2.0f * fmaf(as, as, 1e-4f));

    __syncthreads();

    const int pp  = tile * 256 + tid;   // pixel in plane, 0..4095
    const int wpx = pp & 63;
    const int hpx = pp >> 6;

    // Strip-table row bases: idx(i,j) = baseRow[i] - 8j  (dx = wpx-8j, dy = hpx-8i)
    int baseRow[8];
    #pragma unroll
    for (int i = 0; i < 8; ++i)
        baseRow[i] = (hpx + 56 - 8 * i) * 120 + (wpx + 56);

    float acc = -INFINITY;

    #pragma unroll 2
    for (int i = 0; i < 8; ++i) {
        #pragma unroll
        for (int j = 0; j < 8; ++j) {
            const float4 q = prm[i * 8 + j];          // wave-uniform broadcast
            const float2 g = tab2[baseRow[i] - 8 * j];// coalesced, L1/L2-hit
            const float d   = g.y - q.z;              // in [-2pi, 2pi]
            const float ang = fminf(fabsf(d), TWO_PI_F - fabsf(d)); // [0,pi]
            const float aa  = ang * ang;
            const float t   = g.x - q.y;
            const float arg = fmaf(-(t * t), inv2rs,
                              fmaf(-aa, inv2as, q.x));
            acc = fmaxf(acc, arg);
        }
    }

    // Mask-point epilogue: center pixels (h%8==0 && w%8==0) get ang=0 for
    // their own node; that term is lx - rm^2*inv2rs and dominates the
    // unfixed in-loop value.
    if (((wpx & 7) | (hpx & 7)) == 0) {
        const float4 q = prm[(hpx >> 3) * 8 + (wpx >> 3)];
        acc = fmaxf(acc, fmaf(-(q.y * q.y), inv2rs, q.x));
    }

    out[bc * 4096 + pp] = __expf(acc);
}

extern "C" void kernel_launch(void* const* d_in, const int* in_sizes, int n_in,
                              void* d_out, int out_size, void* d_ws, size_t ws_size,
                              hipStream_t stream) {
    const float* x     = (const float*)d_in[0];
    const float* rmean = (const float*)d_in[1];
    const float* amean = (const float*)d_in[2];
    const float* rstd  = (const float*)d_in[3];
    const float* astd  = (const float*)d_in[4];
    float* out  = (float*)d_out;
    float2* tab2 = (float2*)d_ws;       // 115.2 KB of scratch; rebuilt per call

    lrp_geom<<<57, 256, 0, stream>>>(tab2);
    // 128 planes x 16 blocks (256 px each) = 2048 blocks -> 8 waves/SIMD.
    lrp_fwd<<<2048, 256, 0, stream>>>(x, rmean, amean, rstd, astd, tab2, out);
}